// Round 1
// baseline (266.998 us; speedup 1.0000x reference)
//
#include <hip/hip_runtime.h>
#include <stdint.h>

// ---------------------------------------------------------------------------
// threefry2x32 (JAX): 20 rounds, key schedule ks = {k0, k1, k0^k1^0x1BD11BDA}
// ---------------------------------------------------------------------------
struct U2 { uint32_t a, b; };

__host__ __device__ inline U2 tf2x32(uint32_t k0, uint32_t k1, uint32_t x0, uint32_t x1) {
  uint32_t k2 = k0 ^ k1 ^ 0x1BD11BDAu;
#define TFR(r) { x0 += x1; x1 = (x1 << (r)) | (x1 >> (32 - (r))); x1 ^= x0; }
  x0 += k0; x1 += k1;
  TFR(13) TFR(15) TFR(26) TFR(6)  x0 += k1; x1 += k2 + 1u;
  TFR(17) TFR(29) TFR(16) TFR(24) x0 += k2; x1 += k0 + 2u;
  TFR(13) TFR(15) TFR(26) TFR(6)  x0 += k0; x1 += k1 + 3u;
  TFR(17) TFR(29) TFR(16) TFR(24) x0 += k1; x1 += k2 + 4u;
  TFR(13) TFR(15) TFR(26) TFR(6)  x0 += k2; x1 += k0 + 5u;
#undef TFR
  return {x0, x1};
}

// partitionable random_bits(key, 32, shape): element j -> block (0, j), fold x0^x1
__device__ __forceinline__ uint32_t rbits(uint32_t k0, uint32_t k1, uint32_t j) {
  U2 r = tf2x32(k0, k1, 0u, j);
  return r.a ^ r.b;
}

// uniform [0,1): (bits>>9)|1.0f bits, bitcast, -1.0  (exact, no rounding)
__device__ __forceinline__ float bits_to_u01(uint32_t bits) {
  return __uint_as_float(0x3F800000u | (bits >> 9)) - 1.0f;
}

// uniform [lo, 1) with lo = nextafter(-1,0); maxval-minval rounds to exactly 2.0f
__device__ __forceinline__ float bits_to_upm1(uint32_t bits) {
  const float LO = -0.99999994f;
  float f = bits_to_u01(bits);
  return fmaxf(LO, f * 2.0f + LO);   // f*2 exact -> fma==mul+add, no ambiguity
}

// XLA ErfInv32 (Giles): w = -log1p(-x*x)
__device__ __forceinline__ float erfinv32(float x) {
  float w = -log1pf(-x * x);
  float p;
  if (w < 5.0f) {
    w -= 2.5f;
    p = 2.81022636e-08f;
    p = fmaf(p, w, 3.43273939e-07f);
    p = fmaf(p, w, -3.5233877e-06f);
    p = fmaf(p, w, -4.39150654e-06f);
    p = fmaf(p, w, 0.00021858087f);
    p = fmaf(p, w, -0.00125372503f);
    p = fmaf(p, w, -0.00417768164f);
    p = fmaf(p, w, 0.246640727f);
    p = fmaf(p, w, 1.50140941f);
  } else {
    w = sqrtf(w) - 3.0f;
    p = -0.000200214257f;
    p = fmaf(p, w, 0.000100950558f);
    p = fmaf(p, w, 0.00134934322f);
    p = fmaf(p, w, -0.00367342844f);
    p = fmaf(p, w, 0.00573950773f);
    p = fmaf(p, w, -0.0076224613f);
    p = fmaf(p, w, 0.00943887047f);
    p = fmaf(p, w, 1.00167406f);
    p = fmaf(p, w, 2.83297682f);
  }
  return p * x;
}

__device__ __forceinline__ float normal_from_bits(uint32_t bits) {
  return 1.41421356f * erfinv32(bits_to_upm1(bits));  // sqrt(2) as f32
}

// jax.nn.softplus = logaddexp(x, 0) = max(x,0) + log1p(exp(-|x|))
__device__ __forceinline__ float softplusf(float x) {
  return fmaxf(x, 0.0f) + log1pf(expf(-fabsf(x)));
}

// ---------------------------------------------------------------------------
// Stages 1-4: unpool (gather DEG=4, sampled weights) + BN(B=16 per node) +
// ReLU + dropout. Input xin: batch-major [16,nc] if xin_bm, else node-major
// [nc,16]. Output node-major [nf,16].
// ---------------------------------------------------------------------------
__global__ __launch_bounds__(256) void stage_mid(
    const float* __restrict__ xin, int xin_bm, int nc, int nf,
    const int* __restrict__ ii, const float* __restrict__ mu,
    const float* __restrict__ rho, const float* __restrict__ gg,
    const float* __restrict__ bbp, float* __restrict__ out,
    uint32_t kw0, uint32_t kw1, uint32_t kd0, uint32_t kd1)
{
  int f = blockIdx.x * blockDim.x + threadIdx.x;
  if (f >= nf) return;

  // sample the 4 edge weights: w = mu + softplus(rho) * (sqrt2 * erfinv(u))
  float w[4]; int idx[4];
#pragma unroll
  for (int d = 0; d < 4; ++d) {
    uint32_t e = 4u * (uint32_t)f + (uint32_t)d;     // flat index into [E,1,1]
    float eps = normal_from_bits(rbits(kw0, kw1, e));
    w[d] = fmaf(softplusf(rho[e]), eps, mu[e]);
    idx[d] = ii[e];
  }

  float y[16];
#pragma unroll
  for (int b = 0; b < 16; ++b) y[b] = 0.0f;
  if (xin_bm) {
#pragma unroll
    for (int b = 0; b < 16; ++b) {
      float s = 0.0f;
#pragma unroll
      for (int d = 0; d < 4; ++d) s = fmaf(xin[b * nc + idx[d]], w[d], s);
      y[b] = s;
    }
  } else {
#pragma unroll
    for (int d = 0; d < 4; ++d) {
      const float4* xv = reinterpret_cast<const float4*>(xin) + (size_t)idx[d] * 4;
#pragma unroll
      for (int q = 0; q < 4; ++q) {
        float4 a = xv[q];
        y[4 * q + 0] = fmaf(a.x, w[d], y[4 * q + 0]);
        y[4 * q + 1] = fmaf(a.y, w[d], y[4 * q + 1]);
        y[4 * q + 2] = fmaf(a.z, w[d], y[4 * q + 2]);
        y[4 * q + 3] = fmaf(a.w, w[d], y[4 * q + 3]);
      }
    }
  }

  // BatchNorm over the 16 batch values of this node
  float m = 0.0f;
#pragma unroll
  for (int b = 0; b < 16; ++b) m += y[b];
  m *= 0.0625f;
  float v = 0.0f;
#pragma unroll
  for (int b = 0; b < 16; ++b) { float dd = y[b] - m; v = fmaf(dd, dd, v); }
  v *= 0.0625f;
  float sc = rsqrtf(v + 1e-5f) * gg[f];
  float bi = bbp[f];

  // ReLU + dropout (mask flat index b*nf + f); write node-major
  float4* o4 = reinterpret_cast<float4*>(out) + (size_t)f * 4;
#pragma unroll
  for (int q = 0; q < 4; ++q) {
    float r[4];
#pragma unroll
    for (int k = 0; k < 4; ++k) {
      int b = 4 * q + k;
      float u = bits_to_u01(rbits(kd0, kd1, (uint32_t)b * (uint32_t)nf + (uint32_t)f));
      float h = fmaxf(fmaf(y[b] - m, sc, bi), 0.0f);
      r[k] = (u < 0.9f) ? h * (1.0f / 0.9f) : 0.0f;
    }
    o4[q] = make_float4(r[0], r[1], r[2], r[3]);
  }
}

// ---------------------------------------------------------------------------
// Stage 5: unpool to [16, 524288, 3]; no BN/dropout. xin node-major [nc,16].
// ---------------------------------------------------------------------------
__global__ __launch_bounds__(256) void stage_final(
    const float* __restrict__ xin, const int* __restrict__ ii,
    const float* __restrict__ mu, const float* __restrict__ rho,
    float* __restrict__ out, uint32_t kw0, uint32_t kw1)
{
  const int nf = 524288;
  int f = blockIdx.x * blockDim.x + threadIdx.x;
  if (f >= nf) return;

  float w[4][3]; int idx[4];
#pragma unroll
  for (int d = 0; d < 4; ++d) {
    uint32_t e = 4u * (uint32_t)f + (uint32_t)d;
    idx[d] = ii[e];
#pragma unroll
    for (int o = 0; o < 3; ++o) {
      uint32_t j = 3u * e + (uint32_t)o;            // flat index into [E,1,3]
      float eps = normal_from_bits(rbits(kw0, kw1, j));
      w[d][o] = fmaf(softplusf(rho[j]), eps, mu[j]);
    }
  }

  float acc[16][3];
#pragma unroll
  for (int b = 0; b < 16; ++b)
#pragma unroll
    for (int o = 0; o < 3; ++o) acc[b][o] = 0.0f;

#pragma unroll
  for (int d = 0; d < 4; ++d) {
    const float4* xv = reinterpret_cast<const float4*>(xin) + (size_t)idx[d] * 4;
#pragma unroll
    for (int q = 0; q < 4; ++q) {
      float4 a = xv[q];
      float av[4] = {a.x, a.y, a.z, a.w};
#pragma unroll
      for (int k = 0; k < 4; ++k)
#pragma unroll
        for (int o = 0; o < 3; ++o)
          acc[4 * q + k][o] = fmaf(av[k], w[d][o], acc[4 * q + k][o]);
    }
  }

#pragma unroll
  for (int b = 0; b < 16; ++b) {
    size_t base = ((size_t)b * nf + (size_t)f) * 3;
    out[base + 0] = acc[b][0];
    out[base + 1] = acc[b][1];
    out[base + 2] = acc[b][2];
  }
}

// ---------------------------------------------------------------------------
// KL: sum over all weights of 0.5*(sigma^2 + mu^2) - log(sigma) - 0.5
// Deterministic two-stage reduction (no float atomics).
// ---------------------------------------------------------------------------
__global__ __launch_bounds__(256) void kl_partial(
    const float* __restrict__ mu, const float* __restrict__ rho, int n,
    float* __restrict__ partial)
{
  float s = 0.0f;
  for (int i = blockIdx.x * 256 + threadIdx.x; i < n; i += gridDim.x * 256) {
    float mm = mu[i];
    float sp = softplusf(rho[i]);
    s += 0.5f * (sp * sp + mm * mm) - logf(sp) - 0.5f;
  }
  __shared__ float sm[256];
  sm[threadIdx.x] = s;
  __syncthreads();
  for (int off = 128; off > 0; off >>= 1) {
    if (threadIdx.x < off) sm[threadIdx.x] += sm[threadIdx.x + off];
    __syncthreads();
  }
  if (threadIdx.x == 0) partial[blockIdx.x] = sm[0];
}

__global__ __launch_bounds__(256) void kl_final(
    const float* __restrict__ p, int n, float* __restrict__ dst)
{
  float s = 0.0f;
  for (int i = threadIdx.x; i < n; i += 256) s += p[i];
  __shared__ float sm[256];
  sm[threadIdx.x] = s;
  __syncthreads();
  for (int off = 128; off > 0; off >>= 1) {
    if (threadIdx.x < off) sm[threadIdx.x] += sm[threadIdx.x + off];
    __syncthreads();
  }
  if (threadIdx.x == 0) *dst = sm[0];
}

// ---------------------------------------------------------------------------
extern "C" void kernel_launch(void* const* d_in, const int* in_sizes, int n_in,
                              void* d_out, int out_size, void* d_ws, size_t ws_size,
                              hipStream_t stream) {
  // setup_inputs dict order:
  // 0:x  | per stage i: io, ii, mu, rho, (g, b for i<4)
  const float* x0   = (const float*)d_in[0];
  const int*   ii1  = (const int*)d_in[2];
  const float* mu1  = (const float*)d_in[3];
  const float* rho1 = (const float*)d_in[4];
  const float* g1   = (const float*)d_in[5];
  const float* b1   = (const float*)d_in[6];
  const int*   ii2  = (const int*)d_in[8];
  const float* mu2  = (const float*)d_in[9];
  const float* rho2 = (const float*)d_in[10];
  const float* g2   = (const float*)d_in[11];
  const float* b2   = (const float*)d_in[12];
  const int*   ii3  = (const int*)d_in[14];
  const float* mu3  = (const float*)d_in[15];
  const float* rho3 = (const float*)d_in[16];
  const float* g3   = (const float*)d_in[17];
  const float* b3   = (const float*)d_in[18];
  const int*   ii4  = (const int*)d_in[20];
  const float* mu4  = (const float*)d_in[21];
  const float* rho4 = (const float*)d_in[22];
  const float* g4   = (const float*)d_in[23];
  const float* b4   = (const float*)d_in[24];
  const int*   ii5  = (const int*)d_in[26];
  const float* mu5  = (const float*)d_in[27];
  const float* rho5 = (const float*)d_in[28];

  float* out = (float*)d_out;
  float* ws  = (float*)d_ws;

  // workspace: node-major intermediates + KL partials
  float* h1  = ws;                       // [2048 *16]
  float* h2  = h1 + 2048  * 16;          // [8192 *16]
  float* h3  = h2 + 8192  * 16;          // [32768*16]
  float* h4  = h3 + 32768 * 16;          // [131072*16]
  float* klp = h4 + 131072 * 16;         // [5*128]

  // derive keys = jax.random.split(jax.random.key(42), 10) -- partitionable:
  // keys[i] = threefry2x32((0,42), (0, i))
  uint32_t K[10][2];
  for (uint32_t i = 0; i < 10; ++i) {
    U2 r = tf2x32(0u, 42u, 0u, i);
    K[i][0] = r.a; K[i][1] = r.b;
  }

  dim3 blk(256);
  stage_mid<<<2048 / 256, blk, 0, stream>>>(x0, 1, 512, 2048, ii1, mu1, rho1, g1, b1, h1,
                                            K[0][0], K[0][1], K[1][0], K[1][1]);
  stage_mid<<<8192 / 256, blk, 0, stream>>>(h1, 0, 2048, 8192, ii2, mu2, rho2, g2, b2, h2,
                                            K[2][0], K[2][1], K[3][0], K[3][1]);
  stage_mid<<<32768 / 256, blk, 0, stream>>>(h2, 0, 8192, 32768, ii3, mu3, rho3, g3, b3, h3,
                                             K[4][0], K[4][1], K[5][0], K[5][1]);
  stage_mid<<<131072 / 256, blk, 0, stream>>>(h3, 0, 32768, 131072, ii4, mu4, rho4, g4, b4, h4,
                                              K[6][0], K[6][1], K[7][0], K[7][1]);
  stage_final<<<524288 / 256, blk, 0, stream>>>(h4, ii5, mu5, rho5, out, K[8][0], K[8][1]);

  // KL over all 5 stages' (mu, rho)
  kl_partial<<<128, blk, 0, stream>>>(mu1, rho1, 8192,    klp + 0 * 128);
  kl_partial<<<128, blk, 0, stream>>>(mu2, rho2, 32768,   klp + 1 * 128);
  kl_partial<<<128, blk, 0, stream>>>(mu3, rho3, 131072,  klp + 2 * 128);
  kl_partial<<<128, blk, 0, stream>>>(mu4, rho4, 524288,  klp + 3 * 128);
  kl_partial<<<128, blk, 0, stream>>>(mu5, rho5, 6291456, klp + 4 * 128);
  kl_final<<<1, blk, 0, stream>>>(klp, 640, out + (size_t)16 * 524288 * 3);
}

// Round 2
// 123.042 us; speedup vs baseline: 2.1700x; 2.1700x over previous
//
#include <hip/hip_runtime.h>
#include <stdint.h>

// ---------------------------------------------------------------------------
// threefry2x32 (JAX): 20 rounds, key schedule ks = {k0, k1, k0^k1^0x1BD11BDA}
// ---------------------------------------------------------------------------
struct U2 { uint32_t a, b; };

__host__ __device__ inline U2 tf2x32(uint32_t k0, uint32_t k1, uint32_t x0, uint32_t x1) {
  uint32_t k2 = k0 ^ k1 ^ 0x1BD11BDAu;
#define TFR(r) { x0 += x1; x1 = (x1 << (r)) | (x1 >> (32 - (r))); x1 ^= x0; }
  x0 += k0; x1 += k1;
  TFR(13) TFR(15) TFR(26) TFR(6)  x0 += k1; x1 += k2 + 1u;
  TFR(17) TFR(29) TFR(16) TFR(24) x0 += k2; x1 += k0 + 2u;
  TFR(13) TFR(15) TFR(26) TFR(6)  x0 += k0; x1 += k1 + 3u;
  TFR(17) TFR(29) TFR(16) TFR(24) x0 += k1; x1 += k2 + 4u;
  TFR(13) TFR(15) TFR(26) TFR(6)  x0 += k2; x1 += k0 + 5u;
#undef TFR
  return {x0, x1};
}

// partitionable random_bits(key, 32, shape): element j -> block (0, j), fold x0^x1
__device__ __forceinline__ uint32_t rbits(uint32_t k0, uint32_t k1, uint32_t j) {
  U2 r = tf2x32(k0, k1, 0u, j);
  return r.a ^ r.b;
}

// uniform [0,1): (bits>>9)|1.0f bits, bitcast, -1.0  (exact, no rounding)
__device__ __forceinline__ float bits_to_u01(uint32_t bits) {
  return __uint_as_float(0x3F800000u | (bits >> 9)) - 1.0f;
}

// uniform [lo, 1) with lo = nextafter(-1,0); maxval-minval rounds to exactly 2.0f
__device__ __forceinline__ float bits_to_upm1(uint32_t bits) {
  const float LO = -0.99999994f;
  float f = bits_to_u01(bits);
  return fmaxf(LO, f * 2.0f + LO);
}

// XLA ErfInv32 (Giles): w = -log1p(-x*x)
__device__ __forceinline__ float erfinv32(float x) {
  float w = -log1pf(-x * x);
  float p;
  if (w < 5.0f) {
    w -= 2.5f;
    p = 2.81022636e-08f;
    p = fmaf(p, w, 3.43273939e-07f);
    p = fmaf(p, w, -3.5233877e-06f);
    p = fmaf(p, w, -4.39150654e-06f);
    p = fmaf(p, w, 0.00021858087f);
    p = fmaf(p, w, -0.00125372503f);
    p = fmaf(p, w, -0.00417768164f);
    p = fmaf(p, w, 0.246640727f);
    p = fmaf(p, w, 1.50140941f);
  } else {
    w = sqrtf(w) - 3.0f;
    p = -0.000200214257f;
    p = fmaf(p, w, 0.000100950558f);
    p = fmaf(p, w, 0.00134934322f);
    p = fmaf(p, w, -0.00367342844f);
    p = fmaf(p, w, 0.00573950773f);
    p = fmaf(p, w, -0.0076224613f);
    p = fmaf(p, w, 0.00943887047f);
    p = fmaf(p, w, 1.00167406f);
    p = fmaf(p, w, 2.83297682f);
  }
  return p * x;
}

__device__ __forceinline__ float normal_from_bits(uint32_t bits) {
  return 1.41421356f * erfinv32(bits_to_upm1(bits));  // sqrt(2) as f32
}

// jax.nn.softplus = logaddexp(x, 0) = max(x,0) + log1p(exp(-|x|))
__device__ __forceinline__ float softplusf(float x) {
  return fmaxf(x, 0.0f) + log1pf(expf(-fabsf(x)));
}

// KL term for one weight: 0.5*(sp^2 + mu^2) - log(sp) - 0.5
__device__ __forceinline__ float kl_term(float mu, float sp) {
  return fmaf(0.5f, fmaf(sp, sp, mu * mu), -logf(sp) - 0.5f);
}

// block-level tree reduction of one float per thread -> partial[blockIdx.x]
__device__ __forceinline__ void block_reduce_store(float v, float* partial) {
  __shared__ float sm[256];
  sm[threadIdx.x] = v;
  __syncthreads();
  for (int off = 128; off > 0; off >>= 1) {
    if (threadIdx.x < off) sm[threadIdx.x] += sm[threadIdx.x + off];
    __syncthreads();
  }
  if (threadIdx.x == 0) partial[blockIdx.x] = sm[0];
}

// ---------------------------------------------------------------------------
// Stages 1-4: unpool (gather DEG=4, sampled weights) + BN(B=16 per node) +
// ReLU + dropout + fused per-block KL partial. Input xin: batch-major [16,nc]
// if xin_bm, else node-major [nc,16]. Output node-major [nf,16].
// Grids here are exact multiples of 256 (nf in {2048,8192,32768,131072}).
// ---------------------------------------------------------------------------
__global__ __launch_bounds__(256) void stage_mid(
    const float* __restrict__ xin, int xin_bm, int nc, int nf,
    const int* __restrict__ ii, const float* __restrict__ mu,
    const float* __restrict__ rho, const float* __restrict__ gg,
    const float* __restrict__ bbp, float* __restrict__ out,
    float* __restrict__ klp,
    uint32_t kw0, uint32_t kw1, uint32_t kd0, uint32_t kd1)
{
  int f = blockIdx.x * blockDim.x + threadIdx.x;   // always < nf (exact grid)

  // vector loads: 4 contiguous edges per fine node
  int4   iv = reinterpret_cast<const int4*>(ii)[f];
  float4 m4 = reinterpret_cast<const float4*>(mu)[f];
  float4 r4 = reinterpret_cast<const float4*>(rho)[f];
  int   idx[4] = {iv.x, iv.y, iv.z, iv.w};
  float mus[4] = {m4.x, m4.y, m4.z, m4.w};
  float rhs[4] = {r4.x, r4.y, r4.z, r4.w};

  // sample weights + accumulate KL
  float w[4];
  float kl = 0.0f;
#pragma unroll
  for (int d = 0; d < 4; ++d) {
    uint32_t e = 4u * (uint32_t)f + (uint32_t)d;   // flat index into [E,1,1]
    float sp  = softplusf(rhs[d]);
    float eps = normal_from_bits(rbits(kw0, kw1, e));
    w[d] = fmaf(sp, eps, mus[d]);
    kl += kl_term(mus[d], sp);
  }

  float y[16];
#pragma unroll
  for (int b = 0; b < 16; ++b) y[b] = 0.0f;
  if (xin_bm) {
#pragma unroll
    for (int b = 0; b < 16; ++b) {
      float s = 0.0f;
#pragma unroll
      for (int d = 0; d < 4; ++d) s = fmaf(xin[b * nc + idx[d]], w[d], s);
      y[b] = s;
    }
  } else {
#pragma unroll
    for (int d = 0; d < 4; ++d) {
      const float4* xv = reinterpret_cast<const float4*>(xin) + (size_t)idx[d] * 4;
#pragma unroll
      for (int q = 0; q < 4; ++q) {
        float4 a = xv[q];
        y[4 * q + 0] = fmaf(a.x, w[d], y[4 * q + 0]);
        y[4 * q + 1] = fmaf(a.y, w[d], y[4 * q + 1]);
        y[4 * q + 2] = fmaf(a.z, w[d], y[4 * q + 2]);
        y[4 * q + 3] = fmaf(a.w, w[d], y[4 * q + 3]);
      }
    }
  }

  // BatchNorm over the 16 batch values of this node
  float m = 0.0f;
#pragma unroll
  for (int b = 0; b < 16; ++b) m += y[b];
  m *= 0.0625f;
  float v = 0.0f;
#pragma unroll
  for (int b = 0; b < 16; ++b) { float dd = y[b] - m; v = fmaf(dd, dd, v); }
  v *= 0.0625f;
  float sc = rsqrtf(v + 1e-5f) * gg[f];
  float bi = bbp[f];

  // ReLU + dropout (mask flat index b*nf + f); write node-major
  float4* o4 = reinterpret_cast<float4*>(out) + (size_t)f * 4;
#pragma unroll
  for (int q = 0; q < 4; ++q) {
    float r[4];
#pragma unroll
    for (int k = 0; k < 4; ++k) {
      int b = 4 * q + k;
      float u = bits_to_u01(rbits(kd0, kd1, (uint32_t)b * (uint32_t)nf + (uint32_t)f));
      float h = fmaxf(fmaf(y[b] - m, sc, bi), 0.0f);
      r[k] = (u < 0.9f) ? h * (1.0f / 0.9f) : 0.0f;
    }
    o4[q] = make_float4(r[0], r[1], r[2], r[3]);
  }

  block_reduce_store(kl, klp);
}

// ---------------------------------------------------------------------------
// Stage 5: unpool to [16, 524288, 3] + fused KL. xin node-major [nc,16].
// ---------------------------------------------------------------------------
__global__ __launch_bounds__(256) void stage_final(
    const float* __restrict__ xin, const int* __restrict__ ii,
    const float* __restrict__ mu, const float* __restrict__ rho,
    float* __restrict__ out, float* __restrict__ klp,
    uint32_t kw0, uint32_t kw1)
{
  const int nf = 524288;
  int f = blockIdx.x * blockDim.x + threadIdx.x;   // exact grid

  int4 iv = reinterpret_cast<const int4*>(ii)[f];
  int idx[4] = {iv.x, iv.y, iv.z, iv.w};

  // 12 contiguous weights per thread: 3 x float4 each for mu, rho
  const float4* mp = reinterpret_cast<const float4*>(mu) + (size_t)f * 3;
  const float4* rp = reinterpret_cast<const float4*>(rho) + (size_t)f * 3;
  float4 ma = mp[0], mb = mp[1], mc = mp[2];
  float4 ra = rp[0], rb = rp[1], rc = rp[2];
  float mus[12] = {ma.x, ma.y, ma.z, ma.w, mb.x, mb.y, mb.z, mb.w, mc.x, mc.y, mc.z, mc.w};
  float rhs[12] = {ra.x, ra.y, ra.z, ra.w, rb.x, rb.y, rb.z, rb.w, rc.x, rc.y, rc.z, rc.w};

  float w[4][3];
  float kl = 0.0f;
#pragma unroll
  for (int d = 0; d < 4; ++d) {
#pragma unroll
    for (int o = 0; o < 3; ++o) {
      int t = 3 * d + o;
      uint32_t j = 12u * (uint32_t)f + (uint32_t)t;  // flat index into [E,1,3]
      float sp  = softplusf(rhs[t]);
      float eps = normal_from_bits(rbits(kw0, kw1, j));
      w[d][o] = fmaf(sp, eps, mus[t]);
      kl += kl_term(mus[t], sp);
    }
  }

  float acc[16][3];
#pragma unroll
  for (int b = 0; b < 16; ++b)
#pragma unroll
    for (int o = 0; o < 3; ++o) acc[b][o] = 0.0f;

#pragma unroll
  for (int d = 0; d < 4; ++d) {
    const float4* xv = reinterpret_cast<const float4*>(xin) + (size_t)idx[d] * 4;
#pragma unroll
    for (int q = 0; q < 4; ++q) {
      float4 a = xv[q];
      float av[4] = {a.x, a.y, a.z, a.w};
#pragma unroll
      for (int k = 0; k < 4; ++k)
#pragma unroll
        for (int o = 0; o < 3; ++o)
          acc[4 * q + k][o] = fmaf(av[k], w[d][o], acc[4 * q + k][o]);
    }
  }

#pragma unroll
  for (int b = 0; b < 16; ++b) {
    size_t base = ((size_t)b * nf + (size_t)f) * 3;
    out[base + 0] = acc[b][0];
    out[base + 1] = acc[b][1];
    out[base + 2] = acc[b][2];
  }

  block_reduce_store(kl, klp);
}

// ---------------------------------------------------------------------------
// Final deterministic reduce of all block partials -> out[KL slot]
// ---------------------------------------------------------------------------
__global__ __launch_bounds__(256) void kl_final(
    const float* __restrict__ p, int n, float* __restrict__ dst)
{
  float s = 0.0f;
  for (int i = threadIdx.x; i < n; i += 256) s += p[i];
  __shared__ float sm[256];
  sm[threadIdx.x] = s;
  __syncthreads();
  for (int off = 128; off > 0; off >>= 1) {
    if (threadIdx.x < off) sm[threadIdx.x] += sm[threadIdx.x + off];
    __syncthreads();
  }
  if (threadIdx.x == 0) *dst = sm[0];
}

// ---------------------------------------------------------------------------
extern "C" void kernel_launch(void* const* d_in, const int* in_sizes, int n_in,
                              void* d_out, int out_size, void* d_ws, size_t ws_size,
                              hipStream_t stream) {
  // setup_inputs dict order: 0:x | per stage i: io, ii, mu, rho, (g, b for i<4)
  const float* x0   = (const float*)d_in[0];
  const int*   ii1  = (const int*)d_in[2];
  const float* mu1  = (const float*)d_in[3];
  const float* rho1 = (const float*)d_in[4];
  const float* g1   = (const float*)d_in[5];
  const float* b1   = (const float*)d_in[6];
  const int*   ii2  = (const int*)d_in[8];
  const float* mu2  = (const float*)d_in[9];
  const float* rho2 = (const float*)d_in[10];
  const float* g2   = (const float*)d_in[11];
  const float* b2   = (const float*)d_in[12];
  const int*   ii3  = (const int*)d_in[14];
  const float* mu3  = (const float*)d_in[15];
  const float* rho3 = (const float*)d_in[16];
  const float* g3   = (const float*)d_in[17];
  const float* b3   = (const float*)d_in[18];
  const int*   ii4  = (const int*)d_in[20];
  const float* mu4  = (const float*)d_in[21];
  const float* rho4 = (const float*)d_in[22];
  const float* g4   = (const float*)d_in[23];
  const float* b4   = (const float*)d_in[24];
  const int*   ii5  = (const int*)d_in[26];
  const float* mu5  = (const float*)d_in[27];
  const float* rho5 = (const float*)d_in[28];

  float* out = (float*)d_out;
  float* ws  = (float*)d_ws;

  // workspace: node-major intermediates + KL partials
  float* h1  = ws;                       // [2048 *16]
  float* h2  = h1 + 2048  * 16;          // [8192 *16]
  float* h3  = h2 + 8192  * 16;          // [32768*16]
  float* h4  = h3 + 32768 * 16;          // [131072*16]
  float* klp = h4 + 131072 * 16;         // [8+32+128+512+2048 = 2728]

  // keys = jax.random.split(jax.random.key(42), 10): keys[i] = tf((0,42),(0,i))
  uint32_t K[10][2];
  for (uint32_t i = 0; i < 10; ++i) {
    U2 r = tf2x32(0u, 42u, 0u, i);
    K[i][0] = r.a; K[i][1] = r.b;
  }

  dim3 blk(256);
  float* klp1 = klp;              // 8
  float* klp2 = klp1 + 8;         // 32
  float* klp3 = klp2 + 32;        // 128
  float* klp4 = klp3 + 128;       // 512
  float* klp5 = klp4 + 512;       // 2048

  stage_mid<<<2048 / 256, blk, 0, stream>>>(x0, 1, 512, 2048, ii1, mu1, rho1, g1, b1, h1,
                                            klp1, K[0][0], K[0][1], K[1][0], K[1][1]);
  stage_mid<<<8192 / 256, blk, 0, stream>>>(h1, 0, 2048, 8192, ii2, mu2, rho2, g2, b2, h2,
                                            klp2, K[2][0], K[2][1], K[3][0], K[3][1]);
  stage_mid<<<32768 / 256, blk, 0, stream>>>(h2, 0, 8192, 32768, ii3, mu3, rho3, g3, b3, h3,
                                             klp3, K[4][0], K[4][1], K[5][0], K[5][1]);
  stage_mid<<<131072 / 256, blk, 0, stream>>>(h3, 0, 32768, 131072, ii4, mu4, rho4, g4, b4, h4,
                                              klp4, K[6][0], K[6][1], K[7][0], K[7][1]);
  stage_final<<<524288 / 256, blk, 0, stream>>>(h4, ii5, mu5, rho5, out, klp5,
                                                K[8][0], K[8][1]);
  kl_final<<<1, blk, 0, stream>>>(klp, 2728, out + (size_t)16 * 524288 * 3);
}

// Round 4
// 111.841 us; speedup vs baseline: 2.3873x; 1.1002x over previous
//
#include <hip/hip_runtime.h>
#include <hip/hip_fp16.h>
#include <stdint.h>

typedef uint32_t u32;
typedef float    f32x4 __attribute__((ext_vector_type(4)));
typedef int      i32x4 __attribute__((ext_vector_type(4)));
typedef uint32_t u32x4 __attribute__((ext_vector_type(4)));

// ---------------------------------------------------------------------------
// threefry2x32 (JAX): 20 rounds, key schedule ks = {k0, k1, k0^k1^0x1BD11BDA}
// ---------------------------------------------------------------------------
struct U2 { u32 a, b; };

__host__ __device__ inline U2 tf2x32(u32 k0, u32 k1, u32 x0, u32 x1) {
  u32 k2 = k0 ^ k1 ^ 0x1BD11BDAu;
#define TFR(r) { x0 += x1; x1 = (x1 << (r)) | (x1 >> (32 - (r))); x1 ^= x0; }
  x0 += k0; x1 += k1;
  TFR(13) TFR(15) TFR(26) TFR(6)  x0 += k1; x1 += k2 + 1u;
  TFR(17) TFR(29) TFR(16) TFR(24) x0 += k2; x1 += k0 + 2u;
  TFR(13) TFR(15) TFR(26) TFR(6)  x0 += k0; x1 += k1 + 3u;
  TFR(17) TFR(29) TFR(16) TFR(24) x0 += k1; x1 += k2 + 4u;
  TFR(13) TFR(15) TFR(26) TFR(6)  x0 += k2; x1 += k0 + 5u;
#undef TFR
  return {x0, x1};
}

// partitionable random_bits(key, 32, shape): element j -> block (0, j), fold x0^x1
__device__ __forceinline__ u32 rbits(u32 k0, u32 k1, u32 j) {
  U2 r = tf2x32(k0, k1, 0u, j);
  return r.a ^ r.b;
}

__device__ __forceinline__ float bits_to_u01(u32 bits) {
  return __uint_as_float(0x3F800000u | (bits >> 9)) - 1.0f;
}

__device__ __forceinline__ float bits_to_upm1(u32 bits) {
  const float LO = -0.99999994f;
  float f = bits_to_u01(bits);
  return fmaxf(LO, f * 2.0f + LO);
}

// XLA ErfInv32 (Giles): w = -log1p(-x*x)
__device__ __forceinline__ float erfinv32(float x) {
  float w = -log1pf(-x * x);
  float p;
  if (w < 5.0f) {
    w -= 2.5f;
    p = 2.81022636e-08f;
    p = fmaf(p, w, 3.43273939e-07f);
    p = fmaf(p, w, -3.5233877e-06f);
    p = fmaf(p, w, -4.39150654e-06f);
    p = fmaf(p, w, 0.00021858087f);
    p = fmaf(p, w, -0.00125372503f);
    p = fmaf(p, w, -0.00417768164f);
    p = fmaf(p, w, 0.246640727f);
    p = fmaf(p, w, 1.50140941f);
  } else {
    w = sqrtf(w) - 3.0f;
    p = -0.000200214257f;
    p = fmaf(p, w, 0.000100950558f);
    p = fmaf(p, w, 0.00134934322f);
    p = fmaf(p, w, -0.00367342844f);
    p = fmaf(p, w, 0.00573950773f);
    p = fmaf(p, w, -0.0076224613f);
    p = fmaf(p, w, 0.00943887047f);
    p = fmaf(p, w, 1.00167406f);
    p = fmaf(p, w, 2.83297682f);
  }
  return p * x;
}

__device__ __forceinline__ float normal_from_bits(u32 bits) {
  return 1.41421356f * erfinv32(bits_to_upm1(bits));
}

__device__ __forceinline__ float softplusf(float x) {
  return fmaxf(x, 0.0f) + log1pf(expf(-fabsf(x)));
}

__device__ __forceinline__ float kl_term(float mu, float sp) {
  return fmaf(0.5f, fmaf(sp, sp, mu * mu), -logf(sp) - 0.5f);
}

__device__ __forceinline__ void block_reduce_store(float v, float* partial) {
  __shared__ float sm[256];
  sm[threadIdx.x] = v;
  __syncthreads();
  for (int off = 128; off > 0; off >>= 1) {
    if (threadIdx.x < off) sm[threadIdx.x] += sm[threadIdx.x + off];
    __syncthreads();
  }
  if (threadIdx.x == 0) partial[blockIdx.x] = sm[0];
}

// 16 halves = one coarse node's batch vector (32 B)
union H16 {
  u32x4 u[2];
  __half h[16];
};

// ---------------------------------------------------------------------------
// Stage 1: input x0 batch-major f32 [16,512] (tiny, cached); out f16 [nf,16]
// ---------------------------------------------------------------------------
__global__ __launch_bounds__(256) void stage_first(
    const float* __restrict__ xin, int nc, int nf,
    const int* __restrict__ ii, const float* __restrict__ mu,
    const float* __restrict__ rho, const float* __restrict__ gg,
    const float* __restrict__ bbp, __half* __restrict__ out,
    float* __restrict__ klp,
    u32 kw0, u32 kw1, u32 kd0, u32 kd1)
{
  int f = blockIdx.x * blockDim.x + threadIdx.x;

  i32x4 iv = __builtin_nontemporal_load(reinterpret_cast<const i32x4*>(ii) + f);
  f32x4 m4 = __builtin_nontemporal_load(reinterpret_cast<const f32x4*>(mu) + f);
  f32x4 r4 = __builtin_nontemporal_load(reinterpret_cast<const f32x4*>(rho) + f);

  float w[4];
  float kl = 0.0f;
#pragma unroll
  for (int d = 0; d < 4; ++d) {
    u32 e = 4u * (u32)f + (u32)d;
    float sp  = softplusf(r4[d]);
    float eps = normal_from_bits(rbits(kw0, kw1, e));
    w[d] = fmaf(sp, eps, m4[d]);
    kl += kl_term(m4[d], sp);
  }

  float y[16];
#pragma unroll
  for (int b = 0; b < 16; ++b) {
    float s = 0.0f;
#pragma unroll
    for (int d = 0; d < 4; ++d) s = fmaf(xin[b * nc + iv[d]], w[d], s);
    y[b] = s;
  }

  // BN over batch
  float m = 0.0f;
#pragma unroll
  for (int b = 0; b < 16; ++b) m += y[b];
  m *= 0.0625f;
  float v = 0.0f;
#pragma unroll
  for (int b = 0; b < 16; ++b) { float dd = y[b] - m; v = fmaf(dd, dd, v); }
  v *= 0.0625f;
  float sc = rsqrtf(v + 1e-5f) * __builtin_nontemporal_load(gg + f);
  float bi = __builtin_nontemporal_load(bbp + f);

  H16 o;
#pragma unroll
  for (int b = 0; b < 16; ++b) {
    float u = bits_to_u01(rbits(kd0, kd1, (u32)b * (u32)nf + (u32)f));
    float h = fmaxf(fmaf(y[b] - m, sc, bi), 0.0f);
    o.h[b] = __float2half_rn((u < 0.9f) ? h * (1.0f / 0.9f) : 0.0f);
  }
  u32x4* op = reinterpret_cast<u32x4*>(out) + (size_t)f * 2;
  __builtin_nontemporal_store(o.u[0], op + 0);
  __builtin_nontemporal_store(o.u[1], op + 1);

  block_reduce_store(kl, klp);
}

// ---------------------------------------------------------------------------
// Stages 2-4: f16 node-major in [nc,16] -> f16 node-major out [nf,16]
// ---------------------------------------------------------------------------
__global__ __launch_bounds__(256) void stage_mid(
    const __half* __restrict__ xin, int nf,
    const int* __restrict__ ii, const float* __restrict__ mu,
    const float* __restrict__ rho, const float* __restrict__ gg,
    const float* __restrict__ bbp, __half* __restrict__ out,
    float* __restrict__ klp,
    u32 kw0, u32 kw1, u32 kd0, u32 kd1)
{
  int f = blockIdx.x * blockDim.x + threadIdx.x;

  i32x4 iv = __builtin_nontemporal_load(reinterpret_cast<const i32x4*>(ii) + f);

  // issue gathers early (cached loads) so weight sampling hides their latency
  H16 xg[4];
#pragma unroll
  for (int d = 0; d < 4; ++d) {
    const u32x4* xp = reinterpret_cast<const u32x4*>(xin) + (size_t)iv[d] * 2;
    xg[d].u[0] = xp[0];
    xg[d].u[1] = xp[1];
  }

  f32x4 m4 = __builtin_nontemporal_load(reinterpret_cast<const f32x4*>(mu) + f);
  f32x4 r4 = __builtin_nontemporal_load(reinterpret_cast<const f32x4*>(rho) + f);

  float w[4];
  float kl = 0.0f;
#pragma unroll
  for (int d = 0; d < 4; ++d) {
    u32 e = 4u * (u32)f + (u32)d;
    float sp  = softplusf(r4[d]);
    float eps = normal_from_bits(rbits(kw0, kw1, e));
    w[d] = fmaf(sp, eps, m4[d]);
    kl += kl_term(m4[d], sp);
  }

  float y[16];
#pragma unroll
  for (int b = 0; b < 16; ++b) y[b] = 0.0f;
#pragma unroll
  for (int d = 0; d < 4; ++d)
#pragma unroll
    for (int b = 0; b < 16; ++b)
      y[b] = fmaf(__half2float(xg[d].h[b]), w[d], y[b]);

  float m = 0.0f;
#pragma unroll
  for (int b = 0; b < 16; ++b) m += y[b];
  m *= 0.0625f;
  float v = 0.0f;
#pragma unroll
  for (int b = 0; b < 16; ++b) { float dd = y[b] - m; v = fmaf(dd, dd, v); }
  v *= 0.0625f;
  float sc = rsqrtf(v + 1e-5f) * __builtin_nontemporal_load(gg + f);
  float bi = __builtin_nontemporal_load(bbp + f);

  H16 o;
#pragma unroll
  for (int b = 0; b < 16; ++b) {
    float u = bits_to_u01(rbits(kd0, kd1, (u32)b * (u32)nf + (u32)f));
    float h = fmaxf(fmaf(y[b] - m, sc, bi), 0.0f);
    o.h[b] = __float2half_rn((u < 0.9f) ? h * (1.0f / 0.9f) : 0.0f);
  }
  u32x4* op = reinterpret_cast<u32x4*>(out) + (size_t)f * 2;
  __builtin_nontemporal_store(o.u[0], op + 0);
  __builtin_nontemporal_store(o.u[1], op + 1);

  block_reduce_store(kl, klp);
}

// ---------------------------------------------------------------------------
// Stage 5: f16 in [nc,16] -> f32 out [16, 524288, 3] + fused KL
// ---------------------------------------------------------------------------
__global__ __launch_bounds__(256) void stage_final(
    const __half* __restrict__ xin, const int* __restrict__ ii,
    const float* __restrict__ mu, const float* __restrict__ rho,
    float* __restrict__ out, float* __restrict__ klp,
    u32 kw0, u32 kw1)
{
  const int nf = 524288;
  int f = blockIdx.x * blockDim.x + threadIdx.x;

  i32x4 iv = __builtin_nontemporal_load(reinterpret_cast<const i32x4*>(ii) + f);

  // gathers first: 4 nodes x 32 B (cached loads; want L2 hits)
  H16 xg[4];
#pragma unroll
  for (int d = 0; d < 4; ++d) {
    const u32x4* xp = reinterpret_cast<const u32x4*>(xin) + (size_t)iv[d] * 2;
    xg[d].u[0] = xp[0];
    xg[d].u[1] = xp[1];
  }

  const f32x4* mp = reinterpret_cast<const f32x4*>(mu) + (size_t)f * 3;
  const f32x4* rp = reinterpret_cast<const f32x4*>(rho) + (size_t)f * 3;
  f32x4 ma = __builtin_nontemporal_load(mp + 0);
  f32x4 mb = __builtin_nontemporal_load(mp + 1);
  f32x4 mc = __builtin_nontemporal_load(mp + 2);
  f32x4 ra = __builtin_nontemporal_load(rp + 0);
  f32x4 rb = __builtin_nontemporal_load(rp + 1);
  f32x4 rc = __builtin_nontemporal_load(rp + 2);
  float mus[12] = {ma[0], ma[1], ma[2], ma[3], mb[0], mb[1], mb[2], mb[3],
                   mc[0], mc[1], mc[2], mc[3]};
  float rhs[12] = {ra[0], ra[1], ra[2], ra[3], rb[0], rb[1], rb[2], rb[3],
                   rc[0], rc[1], rc[2], rc[3]};

  float w[4][3];
  float kl = 0.0f;
#pragma unroll
  for (int d = 0; d < 4; ++d) {
#pragma unroll
    for (int o = 0; o < 3; ++o) {
      int t = 3 * d + o;
      u32 j = 12u * (u32)f + (u32)t;
      float sp  = softplusf(rhs[t]);
      float eps = normal_from_bits(rbits(kw0, kw1, j));
      w[d][o] = fmaf(sp, eps, mus[t]);
      kl += kl_term(mus[t], sp);
    }
  }

  float acc[16][3];
#pragma unroll
  for (int b = 0; b < 16; ++b)
#pragma unroll
    for (int o = 0; o < 3; ++o) acc[b][o] = 0.0f;

#pragma unroll
  for (int d = 0; d < 4; ++d)
#pragma unroll
    for (int b = 0; b < 16; ++b) {
      float xv = __half2float(xg[d].h[b]);
#pragma unroll
      for (int o = 0; o < 3; ++o)
        acc[b][o] = fmaf(xv, w[d][o], acc[b][o]);
    }

#pragma unroll
  for (int b = 0; b < 16; ++b) {
    size_t base = ((size_t)b * nf + (size_t)f) * 3;
    __builtin_nontemporal_store(acc[b][0], out + base + 0);
    __builtin_nontemporal_store(acc[b][1], out + base + 1);
    __builtin_nontemporal_store(acc[b][2], out + base + 2);
  }

  block_reduce_store(kl, klp);
}

// ---------------------------------------------------------------------------
__global__ __launch_bounds__(256) void kl_final(
    const float* __restrict__ p, int n, float* __restrict__ dst)
{
  float s = 0.0f;
  for (int i = threadIdx.x; i < n; i += 256) s += p[i];
  __shared__ float sm[256];
  sm[threadIdx.x] = s;
  __syncthreads();
  for (int off = 128; off > 0; off >>= 1) {
    if (threadIdx.x < off) sm[threadIdx.x] += sm[threadIdx.x + off];
    __syncthreads();
  }
  if (threadIdx.x == 0) *dst = sm[0];
}

// ---------------------------------------------------------------------------
extern "C" void kernel_launch(void* const* d_in, const int* in_sizes, int n_in,
                              void* d_out, int out_size, void* d_ws, size_t ws_size,
                              hipStream_t stream) {
  const float* x0   = (const float*)d_in[0];
  const int*   ii1  = (const int*)d_in[2];
  const float* mu1  = (const float*)d_in[3];
  const float* rho1 = (const float*)d_in[4];
  const float* g1   = (const float*)d_in[5];
  const float* b1   = (const float*)d_in[6];
  const int*   ii2  = (const int*)d_in[8];
  const float* mu2  = (const float*)d_in[9];
  const float* rho2 = (const float*)d_in[10];
  const float* g2   = (const float*)d_in[11];
  const float* b2   = (const float*)d_in[12];
  const int*   ii3  = (const int*)d_in[14];
  const float* mu3  = (const float*)d_in[15];
  const float* rho3 = (const float*)d_in[16];
  const float* g3   = (const float*)d_in[17];
  const float* b3   = (const float*)d_in[18];
  const int*   ii4  = (const int*)d_in[20];
  const float* mu4  = (const float*)d_in[21];
  const float* rho4 = (const float*)d_in[22];
  const float* g4   = (const float*)d_in[23];
  const float* b4   = (const float*)d_in[24];
  const int*   ii5  = (const int*)d_in[26];
  const float* mu5  = (const float*)d_in[27];
  const float* rho5 = (const float*)d_in[28];

  float* out = (float*)d_out;
  float* ws  = (float*)d_ws;

  // workspace layout: KL partials (f32) then f16 intermediates
  float*  klp = ws;                                // [2728] + pad to 4096
  __half* h1  = (__half*)(ws + 4096);              // [2048 *16]
  __half* h2  = h1 + 2048  * 16;                   // [8192 *16]
  __half* h3  = h2 + 8192  * 16;                   // [32768*16]
  __half* h4  = h3 + 32768 * 16;                   // [131072*16]

  float* klp1 = klp;              // 8
  float* klp2 = klp1 + 8;         // 32
  float* klp3 = klp2 + 32;        // 128
  float* klp4 = klp3 + 128;       // 512
  float* klp5 = klp4 + 512;       // 2048

  // keys = jax.random.split(jax.random.key(42), 10): keys[i] = tf((0,42),(0,i))
  u32 K[10][2];
  for (u32 i = 0; i < 10; ++i) {
    U2 r = tf2x32(0u, 42u, 0u, i);
    K[i][0] = r.a; K[i][1] = r.b;
  }

  dim3 blk(256);
  stage_first<<<2048 / 256, blk, 0, stream>>>(x0, 512, 2048, ii1, mu1, rho1, g1, b1, h1,
                                              klp1, K[0][0], K[0][1], K[1][0], K[1][1]);
  stage_mid<<<8192 / 256, blk, 0, stream>>>(h1, 8192, ii2, mu2, rho2, g2, b2, h2,
                                            klp2, K[2][0], K[2][1], K[3][0], K[3][1]);
  stage_mid<<<32768 / 256, blk, 0, stream>>>(h2, 32768, ii3, mu3, rho3, g3, b3, h3,
                                             klp3, K[4][0], K[4][1], K[5][0], K[5][1]);
  stage_mid<<<131072 / 256, blk, 0, stream>>>(h3, 131072, ii4, mu4, rho4, g4, b4, h4,
                                              klp4, K[6][0], K[6][1], K[7][0], K[7][1]);
  stage_final<<<524288 / 256, blk, 0, stream>>>(h4, ii5, mu5, rho5, out, klp5,
                                                K[8][0], K[8][1]);
  kl_final<<<1, blk, 0, stream>>>(klp, 2728, out + (size_t)16 * 524288 * 3);
}

// Round 5
// 97.105 us; speedup vs baseline: 2.7496x; 1.1517x over previous
//
#include <hip/hip_runtime.h>
#include <hip/hip_fp16.h>
#include <stdint.h>

typedef uint32_t u32;
typedef float    f32x4 __attribute__((ext_vector_type(4)));
typedef int      i32x4 __attribute__((ext_vector_type(4)));
typedef uint32_t u32x4 __attribute__((ext_vector_type(4)));

// ---------------------------------------------------------------------------
// threefry2x32 (JAX): 20 rounds, key schedule ks = {k0, k1, k0^k1^0x1BD11BDA}
// Bit-exact (dropout masks depend on it).
// ---------------------------------------------------------------------------
struct U2 { u32 a, b; };

__host__ __device__ inline U2 tf2x32(u32 k0, u32 k1, u32 x0, u32 x1) {
  u32 k2 = k0 ^ k1 ^ 0x1BD11BDAu;
#define TFR(r) { x0 += x1; x1 = (x1 << (r)) | (x1 >> (32 - (r))); x1 ^= x0; }
  x0 += k0; x1 += k1;
  TFR(13) TFR(15) TFR(26) TFR(6)  x0 += k1; x1 += k2 + 1u;
  TFR(17) TFR(29) TFR(16) TFR(24) x0 += k2; x1 += k0 + 2u;
  TFR(13) TFR(15) TFR(26) TFR(6)  x0 += k0; x1 += k1 + 3u;
  TFR(17) TFR(29) TFR(16) TFR(24) x0 += k1; x1 += k2 + 4u;
  TFR(13) TFR(15) TFR(26) TFR(6)  x0 += k2; x1 += k0 + 5u;
#undef TFR
  return {x0, x1};
}

// partitionable random_bits(key, 32, shape): element j -> block (0, j), fold x0^x1
__device__ __forceinline__ u32 rbits(u32 k0, u32 k1, u32 j) {
  U2 r = tf2x32(k0, k1, 0u, j);
  return r.a ^ r.b;
}

__device__ __forceinline__ float bits_to_u01(u32 bits) {
  return __uint_as_float(0x3F800000u | (bits >> 9)) - 1.0f;
}

__device__ __forceinline__ float bits_to_upm1(u32 bits) {
  const float LO = -0.99999994f;
  float f = bits_to_u01(bits);
  return fmaxf(LO, f * 2.0f + LO);
}

// XLA ErfInv32 (Giles). w = -log(1-x^2) via factored form (avoids cancellation);
// hardware v_log_f32 instead of libm log1pf (eps err ~1e-6, tolerance is ~1e-2).
__device__ __forceinline__ float erfinv32(float x) {
  float w = -__logf((1.0f - x) * (1.0f + x));
  float p;
  if (w < 5.0f) {
    w -= 2.5f;
    p = 2.81022636e-08f;
    p = fmaf(p, w, 3.43273939e-07f);
    p = fmaf(p, w, -3.5233877e-06f);
    p = fmaf(p, w, -4.39150654e-06f);
    p = fmaf(p, w, 0.00021858087f);
    p = fmaf(p, w, -0.00125372503f);
    p = fmaf(p, w, -0.00417768164f);
    p = fmaf(p, w, 0.246640727f);
    p = fmaf(p, w, 1.50140941f);
  } else {
    w = sqrtf(w) - 3.0f;
    p = -0.000200214257f;
    p = fmaf(p, w, 0.000100950558f);
    p = fmaf(p, w, 0.00134934322f);
    p = fmaf(p, w, -0.00367342844f);
    p = fmaf(p, w, 0.00573950773f);
    p = fmaf(p, w, -0.0076224613f);
    p = fmaf(p, w, 0.00943887047f);
    p = fmaf(p, w, 1.00167406f);
    p = fmaf(p, w, 2.83297682f);
  }
  return p * x;
}

__device__ __forceinline__ float normal_from_bits(u32 bits) {
  return 1.41421356f * erfinv32(bits_to_upm1(bits));
}

// softplus = max(x,0) + log1p(exp(-|x|)) with hw exp/log (arg in (0,1], safe)
__device__ __forceinline__ float softplusf(float x) {
  return fmaxf(x, 0.0f) + __logf(1.0f + __expf(-fabsf(x)));
}

__device__ __forceinline__ float kl_term(float mu, float sp) {
  return fmaf(0.5f, fmaf(sp, sp, mu * mu), -__logf(sp) - 0.5f);
}

__device__ __forceinline__ void block_reduce_store(float v, float* partial) {
  __shared__ float sm[256];
  sm[threadIdx.x] = v;
  __syncthreads();
  for (int off = 128; off > 0; off >>= 1) {
    if (threadIdx.x < off) sm[threadIdx.x] += sm[threadIdx.x + off];
    __syncthreads();
  }
  if (threadIdx.x == 0) partial[blockIdx.x] = sm[0];
}

// 16 halves = one coarse node's batch vector (32 B)
union H16 {
  u32x4 u[2];
  __half h[16];
};

// ---------------------------------------------------------------------------
// Stage 1: input x0 batch-major f32 [16,512] (tiny, cached); out f16 [nf,16]
// ---------------------------------------------------------------------------
__global__ __launch_bounds__(256, 4) void stage_first(
    const float* __restrict__ xin, int nc, int nf,
    const int* __restrict__ ii, const float* __restrict__ mu,
    const float* __restrict__ rho, const float* __restrict__ gg,
    const float* __restrict__ bbp, __half* __restrict__ out,
    float* __restrict__ klp,
    u32 kw0, u32 kw1, u32 kd0, u32 kd1)
{
  int f = blockIdx.x * blockDim.x + threadIdx.x;

  i32x4 iv = __builtin_nontemporal_load(reinterpret_cast<const i32x4*>(ii) + f);
  f32x4 m4 = __builtin_nontemporal_load(reinterpret_cast<const f32x4*>(mu) + f);
  f32x4 r4 = __builtin_nontemporal_load(reinterpret_cast<const f32x4*>(rho) + f);

  float w[4];
  float kl = 0.0f;
#pragma unroll
  for (int d = 0; d < 4; ++d) {
    u32 e = 4u * (u32)f + (u32)d;
    float sp  = softplusf(r4[d]);
    float eps = normal_from_bits(rbits(kw0, kw1, e));
    w[d] = fmaf(sp, eps, m4[d]);
    kl += kl_term(m4[d], sp);
  }

  float y[16];
#pragma unroll
  for (int b = 0; b < 16; ++b) {
    float s = 0.0f;
#pragma unroll
    for (int d = 0; d < 4; ++d) s = fmaf(xin[b * nc + iv[d]], w[d], s);
    y[b] = s;
  }

  // BN over batch
  float m = 0.0f;
#pragma unroll
  for (int b = 0; b < 16; ++b) m += y[b];
  m *= 0.0625f;
  float v = 0.0f;
#pragma unroll
  for (int b = 0; b < 16; ++b) { float dd = y[b] - m; v = fmaf(dd, dd, v); }
  v *= 0.0625f;
  float sc = rsqrtf(v + 1e-5f) * __builtin_nontemporal_load(gg + f);
  float bi = __builtin_nontemporal_load(bbp + f);

  H16 o;
#pragma unroll
  for (int b = 0; b < 16; ++b) {
    float u = bits_to_u01(rbits(kd0, kd1, (u32)b * (u32)nf + (u32)f));
    float h = fmaxf(fmaf(y[b] - m, sc, bi), 0.0f);
    o.h[b] = __float2half_rn((u < 0.9f) ? h * (1.0f / 0.9f) : 0.0f);
  }
  u32x4* op = reinterpret_cast<u32x4*>(out) + (size_t)f * 2;
  __builtin_nontemporal_store(o.u[0], op + 0);
  __builtin_nontemporal_store(o.u[1], op + 1);

  block_reduce_store(kl, klp);
}

// ---------------------------------------------------------------------------
// Stages 2-4: f16 node-major in [nc,16] -> f16 node-major out [nf,16]
// ---------------------------------------------------------------------------
__global__ __launch_bounds__(256, 4) void stage_mid(
    const __half* __restrict__ xin, int nf,
    const int* __restrict__ ii, const float* __restrict__ mu,
    const float* __restrict__ rho, const float* __restrict__ gg,
    const float* __restrict__ bbp, __half* __restrict__ out,
    float* __restrict__ klp,
    u32 kw0, u32 kw1, u32 kd0, u32 kd1)
{
  int f = blockIdx.x * blockDim.x + threadIdx.x;

  i32x4 iv = __builtin_nontemporal_load(reinterpret_cast<const i32x4*>(ii) + f);

  // issue gathers early (cached loads) so weight sampling hides their latency
  H16 xg[4];
#pragma unroll
  for (int d = 0; d < 4; ++d) {
    const u32x4* xp = reinterpret_cast<const u32x4*>(xin) + (size_t)iv[d] * 2;
    xg[d].u[0] = xp[0];
    xg[d].u[1] = xp[1];
  }

  f32x4 m4 = __builtin_nontemporal_load(reinterpret_cast<const f32x4*>(mu) + f);
  f32x4 r4 = __builtin_nontemporal_load(reinterpret_cast<const f32x4*>(rho) + f);

  float w[4];
  float kl = 0.0f;
#pragma unroll
  for (int d = 0; d < 4; ++d) {
    u32 e = 4u * (u32)f + (u32)d;
    float sp  = softplusf(r4[d]);
    float eps = normal_from_bits(rbits(kw0, kw1, e));
    w[d] = fmaf(sp, eps, m4[d]);
    kl += kl_term(m4[d], sp);
  }

  float y[16];
#pragma unroll
  for (int b = 0; b < 16; ++b) y[b] = 0.0f;
#pragma unroll
  for (int d = 0; d < 4; ++d)
#pragma unroll
    for (int b = 0; b < 16; ++b)
      y[b] = fmaf(__half2float(xg[d].h[b]), w[d], y[b]);

  float m = 0.0f;
#pragma unroll
  for (int b = 0; b < 16; ++b) m += y[b];
  m *= 0.0625f;
  float v = 0.0f;
#pragma unroll
  for (int b = 0; b < 16; ++b) { float dd = y[b] - m; v = fmaf(dd, dd, v); }
  v *= 0.0625f;
  float sc = rsqrtf(v + 1e-5f) * __builtin_nontemporal_load(gg + f);
  float bi = __builtin_nontemporal_load(bbp + f);

  H16 o;
#pragma unroll
  for (int b = 0; b < 16; ++b) {
    float u = bits_to_u01(rbits(kd0, kd1, (u32)b * (u32)nf + (u32)f));
    float h = fmaxf(fmaf(y[b] - m, sc, bi), 0.0f);
    o.h[b] = __float2half_rn((u < 0.9f) ? h * (1.0f / 0.9f) : 0.0f);
  }
  u32x4* op = reinterpret_cast<u32x4*>(out) + (size_t)f * 2;
  __builtin_nontemporal_store(o.u[0], op + 0);
  __builtin_nontemporal_store(o.u[1], op + 1);

  block_reduce_store(kl, klp);
}

// ---------------------------------------------------------------------------
// Stage 5: f16 in [nc,16] -> f32 out [16, 524288, 3] + fused KL
// ---------------------------------------------------------------------------
__global__ __launch_bounds__(256, 4) void stage_final(
    const __half* __restrict__ xin, const int* __restrict__ ii,
    const float* __restrict__ mu, const float* __restrict__ rho,
    float* __restrict__ out, float* __restrict__ klp,
    u32 kw0, u32 kw1)
{
  const int nf = 524288;
  int f = blockIdx.x * blockDim.x + threadIdx.x;

  i32x4 iv = __builtin_nontemporal_load(reinterpret_cast<const i32x4*>(ii) + f);

  // gathers first: 4 nodes x 32 B (cached loads; want L2 hits)
  H16 xg[4];
#pragma unroll
  for (int d = 0; d < 4; ++d) {
    const u32x4* xp = reinterpret_cast<const u32x4*>(xin) + (size_t)iv[d] * 2;
    xg[d].u[0] = xp[0];
    xg[d].u[1] = xp[1];
  }

  const f32x4* mp = reinterpret_cast<const f32x4*>(mu) + (size_t)f * 3;
  const f32x4* rp = reinterpret_cast<const f32x4*>(rho) + (size_t)f * 3;
  f32x4 ma = __builtin_nontemporal_load(mp + 0);
  f32x4 mb = __builtin_nontemporal_load(mp + 1);
  f32x4 mc = __builtin_nontemporal_load(mp + 2);
  f32x4 ra = __builtin_nontemporal_load(rp + 0);
  f32x4 rb = __builtin_nontemporal_load(rp + 1);
  f32x4 rc = __builtin_nontemporal_load(rp + 2);
  float mus[12] = {ma[0], ma[1], ma[2], ma[3], mb[0], mb[1], mb[2], mb[3],
                   mc[0], mc[1], mc[2], mc[3]};
  float rhs[12] = {ra[0], ra[1], ra[2], ra[3], rb[0], rb[1], rb[2], rb[3],
                   rc[0], rc[1], rc[2], rc[3]};

  float w[4][3];
  float kl = 0.0f;
#pragma unroll
  for (int d = 0; d < 4; ++d) {
#pragma unroll
    for (int o = 0; o < 3; ++o) {
      int t = 3 * d + o;
      u32 j = 12u * (u32)f + (u32)t;
      float sp  = softplusf(rhs[t]);
      float eps = normal_from_bits(rbits(kw0, kw1, j));
      w[d][o] = fmaf(sp, eps, mus[t]);
      kl += kl_term(mus[t], sp);
    }
  }

  float acc[16][3];
#pragma unroll
  for (int b = 0; b < 16; ++b)
#pragma unroll
    for (int o = 0; o < 3; ++o) acc[b][o] = 0.0f;

#pragma unroll
  for (int d = 0; d < 4; ++d)
#pragma unroll
    for (int b = 0; b < 16; ++b) {
      float xv = __half2float(xg[d].h[b]);
#pragma unroll
      for (int o = 0; o < 3; ++o)
        acc[b][o] = fmaf(xv, w[d][o], acc[b][o]);
    }

#pragma unroll
  for (int b = 0; b < 16; ++b) {
    size_t base = ((size_t)b * nf + (size_t)f) * 3;
    __builtin_nontemporal_store(acc[b][0], out + base + 0);
    __builtin_nontemporal_store(acc[b][1], out + base + 1);
    __builtin_nontemporal_store(acc[b][2], out + base + 2);
  }

  block_reduce_store(kl, klp);
}

// ---------------------------------------------------------------------------
__global__ __launch_bounds__(256) void kl_final(
    const float* __restrict__ p, int n, float* __restrict__ dst)
{
  float s = 0.0f;
  for (int i = threadIdx.x; i < n; i += 256) s += p[i];
  __shared__ float sm[256];
  sm[threadIdx.x] = s;
  __syncthreads();
  for (int off = 128; off > 0; off >>= 1) {
    if (threadIdx.x < off) sm[threadIdx.x] += sm[threadIdx.x + off];
    __syncthreads();
  }
  if (threadIdx.x == 0) *dst = sm[0];
}

// ---------------------------------------------------------------------------
extern "C" void kernel_launch(void* const* d_in, const int* in_sizes, int n_in,
                              void* d_out, int out_size, void* d_ws, size_t ws_size,
                              hipStream_t stream) {
  const float* x0   = (const float*)d_in[0];
  const int*   ii1  = (const int*)d_in[2];
  const float* mu1  = (const float*)d_in[3];
  const float* rho1 = (const float*)d_in[4];
  const float* g1   = (const float*)d_in[5];
  const float* b1   = (const float*)d_in[6];
  const int*   ii2  = (const int*)d_in[8];
  const float* mu2  = (const float*)d_in[9];
  const float* rho2 = (const float*)d_in[10];
  const float* g2   = (const float*)d_in[11];
  const float* b2   = (const float*)d_in[12];
  const int*   ii3  = (const int*)d_in[14];
  const float* mu3  = (const float*)d_in[15];
  const float* rho3 = (const float*)d_in[16];
  const float* g3   = (const float*)d_in[17];
  const float* b3   = (const float*)d_in[18];
  const int*   ii4  = (const int*)d_in[20];
  const float* mu4  = (const float*)d_in[21];
  const float* rho4 = (const float*)d_in[22];
  const float* g4   = (const float*)d_in[23];
  const float* b4   = (const float*)d_in[24];
  const int*   ii5  = (const int*)d_in[26];
  const float* mu5  = (const float*)d_in[27];
  const float* rho5 = (const float*)d_in[28];

  float* out = (float*)d_out;
  float* ws  = (float*)d_ws;

  // workspace layout: KL partials (f32) then f16 intermediates
  float*  klp = ws;                                // [2728] + pad to 4096
  __half* h1  = (__half*)(ws + 4096);              // [2048 *16]
  __half* h2  = h1 + 2048  * 16;                   // [8192 *16]
  __half* h3  = h2 + 8192  * 16;                   // [32768*16]
  __half* h4  = h3 + 32768 * 16;                   // [131072*16]

  float* klp1 = klp;              // 8
  float* klp2 = klp1 + 8;         // 32
  float* klp3 = klp2 + 32;        // 128
  float* klp4 = klp3 + 128;       // 512
  float* klp5 = klp4 + 512;       // 2048

  // keys = jax.random.split(jax.random.key(42), 10): keys[i] = tf((0,42),(0,i))
  u32 K[10][2];
  for (u32 i = 0; i < 10; ++i) {
    U2 r = tf2x32(0u, 42u, 0u, i);
    K[i][0] = r.a; K[i][1] = r.b;
  }

  dim3 blk(256);
  stage_first<<<2048 / 256, blk, 0, stream>>>(x0, 512, 2048, ii1, mu1, rho1, g1, b1, h1,
                                              klp1, K[0][0], K[0][1], K[1][0], K[1][1]);
  stage_mid<<<8192 / 256, blk, 0, stream>>>(h1, 8192, ii2, mu2, rho2, g2, b2, h2,
                                            klp2, K[2][0], K[2][1], K[3][0], K[3][1]);
  stage_mid<<<32768 / 256, blk, 0, stream>>>(h2, 32768, ii3, mu3, rho3, g3, b3, h3,
                                             klp3, K[4][0], K[4][1], K[5][0], K[5][1]);
  stage_mid<<<131072 / 256, blk, 0, stream>>>(h3, 131072, ii4, mu4, rho4, g4, b4, h4,
                                              klp4, K[6][0], K[6][1], K[7][0], K[7][1]);
  stage_final<<<524288 / 256, blk, 0, stream>>>(h4, ii5, mu5, rho5, out, klp5,
                                                K[8][0], K[8][1]);
  kl_final<<<1, blk, 0, stream>>>(klp, 2728, out + (size_t)16 * 524288 * 3);
}